// Round 1
// baseline (605.773 us; speedup 1.0000x reference)
//
#include <hip/hip_runtime.h>
#include <hip/hip_bf16.h>

#define EMBED 1024
#define THREE_EMBED 3072
#define NHEAD 16
#define HDIM 64
#define MTOT 16384
#define LTOT 16383

typedef __attribute__((ext_vector_type(8))) short bf16x8;
typedef __attribute__((ext_vector_type(4))) float f32x4;

__device__ __forceinline__ unsigned short f2b(float f) {
  union { float f; unsigned u; } v; v.f = f;
  unsigned r = v.u + 0x7fffu + ((v.u >> 16) & 1u);
  return (unsigned short)(r >> 16);
}
__device__ __forceinline__ float b2f(unsigned short h) {
  union { unsigned u; float f; } v; v.u = ((unsigned)h) << 16;
  return v.f;
}

// ---------------------------------------------------------------------------
// GEMM1: qkv = xp @ qkv_w^T + qkv_b   (16384x1024)x(3072x1024)^T -> bf16 out
// 128x128 tile, BK=32, 4 waves (2x2), each wave 64x64 via 4x4 MFMA 16x16x32.
// ---------------------------------------------------------------------------
__global__ __launch_bounds__(256) void gemm_qkv(
    const float* __restrict__ x, const float* __restrict__ padding,
    const float* __restrict__ w, const float* __restrict__ bias,
    unsigned short* __restrict__ out)
{
  __shared__ __align__(16) unsigned short sA[128 * 40];
  __shared__ __align__(16) unsigned short sB[128 * 40];
  const int t = threadIdx.x;
  const int lane = t & 63, wid = t >> 6;
  const int l15 = lane & 15, quad = lane >> 4;
  const int wm = (wid >> 1) * 64, wn = (wid & 1) * 64;
  const int bm = blockIdx.x, bn = blockIdx.y;
  const int r0 = t >> 3, c4 = t & 7;

  f32x4 acc[4][4];
#pragma unroll
  for (int i = 0; i < 4; ++i)
#pragma unroll
    for (int j = 0; j < 4; ++j) acc[i][j] = (f32x4){0.f, 0.f, 0.f, 0.f};

  for (int k0 = 0; k0 < EMBED; k0 += 32) {
    __syncthreads();
#pragma unroll
    for (int ri = 0; ri < 4; ++ri) {
      int r = r0 + 32 * ri;
      int grow = bm * 128 + r;
      const float* src = (grow < LTOT) ? (x + (size_t)grow * EMBED) : padding;
      float4 v = *(const float4*)(src + k0 + c4 * 4);
      ushort4 b;
      b.x = f2b(v.x); b.y = f2b(v.y); b.z = f2b(v.z); b.w = f2b(v.w);
      *(ushort4*)(sA + r * 40 + c4 * 4) = b;
    }
#pragma unroll
    for (int ri = 0; ri < 4; ++ri) {
      int r = r0 + 32 * ri;
      int grow = bn * 128 + r;
      float4 v = *(const float4*)(w + (size_t)grow * EMBED + k0 + c4 * 4);
      ushort4 b;
      b.x = f2b(v.x); b.y = f2b(v.y); b.z = f2b(v.z); b.w = f2b(v.w);
      *(ushort4*)(sB + r * 40 + c4 * 4) = b;
    }
    __syncthreads();
    bf16x8 af[4], bfr[4];
#pragma unroll
    for (int mi = 0; mi < 4; ++mi)
      af[mi] = *(const bf16x8*)(sA + (wm + mi * 16 + l15) * 40 + quad * 8);
#pragma unroll
    for (int ni = 0; ni < 4; ++ni)
      bfr[ni] = *(const bf16x8*)(sB + (wn + ni * 16 + l15) * 40 + quad * 8);
#pragma unroll
    for (int mi = 0; mi < 4; ++mi)
#pragma unroll
      for (int ni = 0; ni < 4; ++ni)
        acc[mi][ni] = __builtin_amdgcn_mfma_f32_16x16x32_bf16(
            af[mi], bfr[ni], acc[mi][ni], 0, 0, 0);
  }

#pragma unroll
  for (int ni = 0; ni < 4; ++ni) {
    int col = bn * 128 + wn + ni * 16 + l15;
    float bv = bias[col];
#pragma unroll
    for (int mi = 0; mi < 4; ++mi) {
#pragma unroll
      for (int reg = 0; reg < 4; ++reg) {
        int row = bm * 128 + wm + mi * 16 + quad * 4 + reg;
        out[(size_t)row * THREE_EMBED + col] = f2b(acc[mi][ni][reg] + bv);
      }
    }
  }
}

// ---------------------------------------------------------------------------
// Attention: one block per (window, head). Gather + RoPE fused into loads.
// K/V staged per 128-key half (online softmax across halves). LDS ~38KB.
// ---------------------------------------------------------------------------
__global__ __launch_bounds__(256) void attn(
    const unsigned short* __restrict__ qkv,
    const float* __restrict__ rope_cos, const float* __restrict__ rope_sin,
    const int* __restrict__ kvi,
    unsigned short* __restrict__ ori)
{
  __shared__ __align__(16) unsigned short sK[128 * 64];   // [key][d] swizzled
  __shared__ __align__(16) unsigned short sV[64 * 128];   // [d][key] swizzled
  __shared__ __align__(16) unsigned short sP[4][16 * 40]; // per-wave P chunk

  const int t = threadIdx.x;
  const int lane = t & 63, wid = t >> 6;
  const int l15 = lane & 15, quad = lane >> 4;
  const int wwin = blockIdx.x >> 4;
  const int h = blockIdx.x & 15;

  f32x4 accO[4][4];
  float mrow[4][4], lrow[4][4];
#pragma unroll
  for (int qt = 0; qt < 4; ++qt) {
#pragma unroll
    for (int nt = 0; nt < 4; ++nt) accO[qt][nt] = (f32x4){0.f, 0.f, 0.f, 0.f};
#pragma unroll
    for (int reg = 0; reg < 4; ++reg) { mrow[qt][reg] = -1e30f; lrow[qt][reg] = 0.f; }
  }

  // Preload Q fragments (RoPE + 1/sqrt(64) scale folded in).
  // A-layout: A[m=l15][k=quad*8+j]; k = d in [0,64) split as ks*32+quad*8+j.
  bf16x8 qa[4][2];
#pragma unroll
  for (int qt = 0; qt < 4; ++qt) {
    int qrow = wid * 64 + qt * 16 + l15;
    int i = wwin * 256 + qrow;
    int g = kvi[i];
    const unsigned short* qp = qkv + (size_t)g * THREE_EMBED + h * HDIM;
    bf16x8 qlo = *(const bf16x8*)(qp + quad * 8);       // d = quad*8 (+j), d<32
    bf16x8 qhi = *(const bf16x8*)(qp + 32 + quad * 8);  // d>=32
    const float* cp = rope_cos + (size_t)i * HDIM;
    const float* sp = rope_sin + (size_t)i * HDIM;
    float c0[8], c1[8], s0[8], s1[8];
    *(float4*)(c0) = *(const float4*)(cp + quad * 8);
    *(float4*)(c0 + 4) = *(const float4*)(cp + quad * 8 + 4);
    *(float4*)(c1) = *(const float4*)(cp + 32 + quad * 8);
    *(float4*)(c1 + 4) = *(const float4*)(cp + 32 + quad * 8 + 4);
    *(float4*)(s0) = *(const float4*)(sp + quad * 8);
    *(float4*)(s0 + 4) = *(const float4*)(sp + quad * 8 + 4);
    *(float4*)(s1) = *(const float4*)(sp + 32 + quad * 8);
    *(float4*)(s1 + 4) = *(const float4*)(sp + 32 + quad * 8 + 4);
    bf16x8 f0, f1;
#pragma unroll
    for (int j = 0; j < 8; ++j) {
      float ql = b2f((unsigned short)qlo[j]);
      float qh = b2f((unsigned short)qhi[j]);
      float v0 = (ql * c0[j] - qh * s0[j]) * 0.125f;
      float v1 = (qh * c1[j] + ql * s1[j]) * 0.125f;
      f0[j] = (short)f2b(v0);
      f1[j] = (short)f2b(v1);
    }
    qa[qt][0] = f0;
    qa[qt][1] = f1;
  }

  for (int half = 0; half < 2; ++half) {
    __syncthreads();
    if (t < 128) {
      // Stage K rows (RoPE'd) -> sK[key][d], 16B chunks swizzled by key&7
      int key = t;
      int i = wwin * 256 + half * 128 + key;
      int g = kvi[i];
      const unsigned short* kp = qkv + (size_t)g * THREE_EMBED + EMBED + h * HDIM;
      const float* cp = rope_cos + (size_t)i * HDIM;
      const float* sp = rope_sin + (size_t)i * HDIM;
#pragma unroll
      for (int c = 0; c < 8; ++c) {
        bf16x8 ka = *(const bf16x8*)(kp + c * 8);
        bf16x8 kb = *(const bf16x8*)(kp + ((c ^ 4) * 8));
        float cc[8], ss[8];
        *(float4*)(cc) = *(const float4*)(cp + c * 8);
        *(float4*)(cc + 4) = *(const float4*)(cp + c * 8 + 4);
        *(float4*)(ss) = *(const float4*)(sp + c * 8);
        *(float4*)(ss + 4) = *(const float4*)(sp + c * 8 + 4);
        union { unsigned short u[8]; uint4 v; } pk;
#pragma unroll
        for (int j = 0; j < 8; ++j) {
          float kd = b2f((unsigned short)ka[j]);
          float kq = b2f((unsigned short)kb[j]);
          float val = (c < 4) ? (kd * cc[j] - kq * ss[j])
                              : (kd * cc[j] + kq * ss[j]);
          pk.u[j] = f2b(val);
        }
        *(uint4*)(sK + key * 64 + ((c ^ (key & 7)) * 8)) = pk.v;
      }
    } else {
      // Stage V transposed -> sV[d][key], key-chunks swizzled by d&7
      int key = t - 128;
      int i = wwin * 256 + half * 128 + key;
      int g = kvi[i];
      const unsigned short* vp = qkv + (size_t)g * THREE_EMBED + 2 * EMBED + h * HDIM;
      int kc3 = key >> 3, k7 = key & 7;
#pragma unroll
      for (int c = 0; c < 8; ++c) {
        bf16x8 va = *(const bf16x8*)(vp + c * 8);
#pragma unroll
        for (int j = 0; j < 8; ++j) {
          int d = c * 8 + j;
          sV[d * 128 + ((kc3 ^ (d & 7)) * 8) + k7] = (unsigned short)va[j];
        }
      }
    }
    __syncthreads();

#pragma unroll
    for (int qt = 0; qt < 4; ++qt) {
      // S = Q K^T for 16 q-rows x 128 keys
      f32x4 accS[8];
#pragma unroll
      for (int nt = 0; nt < 8; ++nt) accS[nt] = (f32x4){0.f, 0.f, 0.f, 0.f};
#pragma unroll
      for (int ks = 0; ks < 2; ++ks) {
#pragma unroll
        for (int nt = 0; nt < 8; ++nt) {
          int key = nt * 16 + l15;
          bf16x8 bk = *(const bf16x8*)(
              sK + key * 64 + (((ks * 4 + quad) ^ (key & 7)) * 8));
          accS[nt] = __builtin_amdgcn_mfma_f32_16x16x32_bf16(
              qa[qt][ks], bk, accS[nt], 0, 0, 0);
        }
      }
      // Online softmax (rows = quad*4+reg, cols across l15 and 8 n-tiles)
#pragma unroll
      for (int reg = 0; reg < 4; ++reg) {
        float mx = accS[0][reg];
#pragma unroll
        for (int nt = 1; nt < 8; ++nt) mx = fmaxf(mx, accS[nt][reg]);
#pragma unroll
        for (int off = 1; off < 16; off <<= 1)
          mx = fmaxf(mx, __shfl_xor(mx, off, 64));
        float mold = mrow[qt][reg];
        float mnew = fmaxf(mold, mx);
        float alpha = __expf(mold - mnew);
        mrow[qt][reg] = mnew;
        float ls = 0.f;
#pragma unroll
        for (int nt = 0; nt < 8; ++nt) {
          float p = __expf(accS[nt][reg] - mnew);
          accS[nt][reg] = p;
          ls += p;
        }
#pragma unroll
        for (int off = 1; off < 16; off <<= 1) ls += __shfl_xor(ls, off, 64);
        lrow[qt][reg] = lrow[qt][reg] * alpha + ls;
#pragma unroll
        for (int nt = 0; nt < 4; ++nt) accO[qt][nt][reg] *= alpha;
      }
      // PV per 32-key chunk: C-layout P -> LDS -> A-layout, MFMA with V
#pragma unroll
      for (int kc = 0; kc < 4; ++kc) {
#pragma unroll
        for (int nt2 = 0; nt2 < 2; ++nt2) {
#pragma unroll
          for (int reg = 0; reg < 4; ++reg) {
            sP[wid][(quad * 4 + reg) * 40 + nt2 * 16 + l15] =
                f2b(accS[kc * 2 + nt2][reg]);
          }
        }
        bf16x8 pa = *(const bf16x8*)(&sP[wid][l15 * 40 + quad * 8]);
#pragma unroll
        for (int nt = 0; nt < 4; ++nt) {
          int d = nt * 16 + l15;
          bf16x8 bv = *(const bf16x8*)(
              sV + d * 128 + (((kc * 4 + quad) ^ (d & 7)) * 8));
          accO[qt][nt] = __builtin_amdgcn_mfma_f32_16x16x32_bf16(
              pa, bv, accO[qt][nt], 0, 0, 0);
        }
      }
    }
  }

  // Epilogue: normalize by l, scatter rows to ori[kv_indices[i]]
#pragma unroll
  for (int qt = 0; qt < 4; ++qt) {
#pragma unroll
    for (int reg = 0; reg < 4; ++reg) {
      int qrow = wid * 64 + qt * 16 + quad * 4 + reg;
      int i = wwin * 256 + qrow;
      int orow = kvi[i];
      float inv = 1.0f / lrow[qt][reg];
      unsigned short* op = ori + (size_t)orow * EMBED + h * HDIM;
#pragma unroll
      for (int nt = 0; nt < 4; ++nt) {
        op[nt * 16 + l15] = f2b(accO[qt][nt][reg] * inv);
      }
    }
  }
}

// ---------------------------------------------------------------------------
// GEMM2: out = ori[:L] @ proj_w^T + proj_b  (A is bf16, out fp32)
// ---------------------------------------------------------------------------
__global__ __launch_bounds__(256) void gemm_proj(
    const unsigned short* __restrict__ A, const float* __restrict__ w,
    const float* __restrict__ bias, float* __restrict__ out)
{
  __shared__ __align__(16) unsigned short sA[128 * 40];
  __shared__ __align__(16) unsigned short sB[128 * 40];
  const int t = threadIdx.x;
  const int lane = t & 63, wid = t >> 6;
  const int l15 = lane & 15, quad = lane >> 4;
  const int wm = (wid >> 1) * 64, wn = (wid & 1) * 64;
  const int bm = blockIdx.x, bn = blockIdx.y;
  const int ra = t >> 2, ca = t & 3;
  const int rb = t >> 3, cb = t & 7;

  f32x4 acc[4][4];
#pragma unroll
  for (int i = 0; i < 4; ++i)
#pragma unroll
    for (int j = 0; j < 4; ++j) acc[i][j] = (f32x4){0.f, 0.f, 0.f, 0.f};

  for (int k0 = 0; k0 < EMBED; k0 += 32) {
    __syncthreads();
#pragma unroll
    for (int ri = 0; ri < 2; ++ri) {
      int r = ra + 64 * ri;
      int grow = bm * 128 + r;
      *(uint4*)(sA + r * 40 + ca * 8) =
          *(const uint4*)(A + (size_t)grow * EMBED + k0 + ca * 8);
    }
#pragma unroll
    for (int ri = 0; ri < 4; ++ri) {
      int r = rb + 32 * ri;
      int grow = bn * 128 + r;
      float4 v = *(const float4*)(w + (size_t)grow * EMBED + k0 + cb * 4);
      ushort4 b;
      b.x = f2b(v.x); b.y = f2b(v.y); b.z = f2b(v.z); b.w = f2b(v.w);
      *(ushort4*)(sB + r * 40 + cb * 4) = b;
    }
    __syncthreads();
    bf16x8 af[4], bfr[4];
#pragma unroll
    for (int mi = 0; mi < 4; ++mi)
      af[mi] = *(const bf16x8*)(sA + (wm + mi * 16 + l15) * 40 + quad * 8);
#pragma unroll
    for (int ni = 0; ni < 4; ++ni)
      bfr[ni] = *(const bf16x8*)(sB + (wn + ni * 16 + l15) * 40 + quad * 8);
#pragma unroll
    for (int mi = 0; mi < 4; ++mi)
#pragma unroll
      for (int ni = 0; ni < 4; ++ni)
        acc[mi][ni] = __builtin_amdgcn_mfma_f32_16x16x32_bf16(
            af[mi], bfr[ni], acc[mi][ni], 0, 0, 0);
  }

#pragma unroll
  for (int ni = 0; ni < 4; ++ni) {
    int col = bn * 128 + wn + ni * 16 + l15;
    float bv = bias[col];
#pragma unroll
    for (int mi = 0; mi < 4; ++mi) {
#pragma unroll
      for (int reg = 0; reg < 4; ++reg) {
        int row = bm * 128 + wm + mi * 16 + quad * 4 + reg;
        if (row < LTOT) out[(size_t)row * EMBED + col] = acc[mi][ni][reg] + bv;
      }
    }
  }
}

// ---------------------------------------------------------------------------
extern "C" void kernel_launch(void* const* d_in, const int* in_sizes, int n_in,
                              void* d_out, int out_size, void* d_ws, size_t ws_size,
                              hipStream_t stream) {
  const float* x        = (const float*)d_in[0];
  const float* qkv_w    = (const float*)d_in[1];
  const float* qkv_b    = (const float*)d_in[2];
  const float* proj_w   = (const float*)d_in[3];
  const float* proj_b   = (const float*)d_in[4];
  const float* padding  = (const float*)d_in[5];
  const float* rope_cos = (const float*)d_in[6];
  const float* rope_sin = (const float*)d_in[7];
  const int*   kvi      = (const int*)d_in[8];
  // d_in[9] = q_indices (== kv_indices), d_in[10] = inv_indices, d_in[11] = ws: unused

  unsigned short* qkv_bf = (unsigned short*)d_ws;                       // 16384x3072 bf16
  unsigned short* ori    = (unsigned short*)((char*)d_ws +
                              (size_t)MTOT * THREE_EMBED * 2);          // 16384x1024 bf16
  float* out = (float*)d_out;

  gemm_qkv<<<dim3(128, 24), 256, 0, stream>>>(x, padding, qkv_w, qkv_b, qkv_bf);
  attn<<<dim3(64 * 16), 256, 0, stream>>>(qkv_bf, rope_cos, rope_sin, kvi, ori);
  gemm_proj<<<dim3(128, 8), 256, 0, stream>>>(ori, proj_w, proj_b, out);
}

// Round 2
// 518.008 us; speedup vs baseline: 1.1694x; 1.1694x over previous
//
#include <hip/hip_runtime.h>
#include <hip/hip_bf16.h>

#define EMBED 1024
#define THREE_EMBED 3072
#define NHEAD 16
#define HDIM 64
#define MTOT 16384
#define LTOT 16383

typedef __attribute__((ext_vector_type(8))) short bf16x8;
typedef __attribute__((ext_vector_type(4))) float f32x4;

__device__ __forceinline__ unsigned short f2b(float f) {
  union { float f; unsigned u; } v; v.f = f;
  unsigned r = v.u + 0x7fffu + ((v.u >> 16) & 1u);
  return (unsigned short)(r >> 16);
}
__device__ __forceinline__ float b2f(unsigned short h) {
  union { unsigned u; float f; } v; v.u = ((unsigned)h) << 16;
  return v.f;
}

// global -> LDS direct copy, 16B per lane. LDS dest must be wave-uniform
// base; HW adds lane*16.
__device__ __forceinline__ void gload16(const void* g, void* l) {
  __builtin_amdgcn_global_load_lds(
      (const __attribute__((address_space(1))) void*)g,
      (__attribute__((address_space(3))) void*)l, 16, 0, 0);
}

// ---------------------------------------------------------------------------
// cast pass: x (+padding row) -> xb bf16 [16384][1024]; qkv_w -> wqb bf16
// ---------------------------------------------------------------------------
__global__ __launch_bounds__(256) void cast_inputs(
    const float* __restrict__ x, const float* __restrict__ padding,
    const float* __restrict__ wq,
    unsigned short* __restrict__ xb, unsigned short* __restrict__ wqb)
{
  const int NX = MTOT * EMBED / 8;        // 2,097,152 groups of 8
  const int NQ = THREE_EMBED * EMBED / 8; // 393,216
  int g = blockIdx.x * 256 + threadIdx.x;
  const int stride = gridDim.x * 256;
  const int total = NX + NQ;
  for (; g < total; g += stride) {
    const float* src;
    unsigned short* dst;
    if (g < NX) {
      size_t e = (size_t)g * 8;
      int row = (int)(e >> 10);
      src = (row < LTOT) ? (x + e) : (padding + (e - (size_t)LTOT * 1024));
      dst = xb + e;
    } else {
      size_t e = (size_t)(g - NX) * 8;
      src = wq + e;
      dst = wqb + e;
    }
    float4 a = *(const float4*)src;
    float4 b = *(const float4*)(src + 4);
    ushort4 u0, u1;
    u0.x = f2b(a.x); u0.y = f2b(a.y); u0.z = f2b(a.z); u0.w = f2b(a.w);
    u1.x = f2b(b.x); u1.y = f2b(b.y); u1.z = f2b(b.z); u1.w = f2b(b.w);
    *(ushort4*)dst = u0;
    *(ushort4*)(dst + 4) = u1;
  }
}

// ---------------------------------------------------------------------------
// GEMM1 (m97 structure): qkv = xb @ wqb^T + qkv_b, all-bf16 operands.
// 128x128 tile, BK=32, global_load_lds width-16 staging into unpadded
// [128][32] LDS, 4 waves x (4x4) 16x16x32 MFMA.
// ---------------------------------------------------------------------------
__global__ __launch_bounds__(256) void gemm_qkv(
    const unsigned short* __restrict__ A, const unsigned short* __restrict__ B,
    const float* __restrict__ bias, unsigned short* __restrict__ out)
{
  __shared__ __align__(16) unsigned short sA[128 * 32];
  __shared__ __align__(16) unsigned short sB[128 * 32];
  const int t = threadIdx.x;
  const int lane = t & 63, wid = t >> 6;
  const int l15 = lane & 15, quad = lane >> 4;
  const int wm = (wid >> 1) * 64, wn = (wid & 1) * 64;
  const int bm = blockIdx.x, bn = blockIdx.y;

  // staging: chunk ci covers LDS bytes [ci*16, ci*16+16); row=ci>>2, col8=(ci&3)*8
  const int r0 = t >> 2, c8 = (t & 3) * 8;
  const unsigned short* gA0 = A + (size_t)(bm * 128 + r0) * EMBED + c8;
  const unsigned short* gB0 = B + (size_t)(bn * 128 + r0) * EMBED + c8;
  unsigned short* lA0 = sA + wid * 512;          // bytes: wid*1024
  unsigned short* lA1 = sA + 2048 + wid * 512;   // bytes: 4096 + wid*1024
  unsigned short* lB0 = sB + wid * 512;
  unsigned short* lB1 = sB + 2048 + wid * 512;

  f32x4 acc[4][4];
#pragma unroll
  for (int i = 0; i < 4; ++i)
#pragma unroll
    for (int j = 0; j < 4; ++j) acc[i][j] = (f32x4){0.f, 0.f, 0.f, 0.f};

  for (int k0 = 0; k0 < EMBED; k0 += 32) {
    __syncthreads();
    gload16(gA0 + k0, lA0);
    gload16(gA0 + 64 * EMBED + k0, lA1);
    gload16(gB0 + k0, lB0);
    gload16(gB0 + 64 * EMBED + k0, lB1);
    __syncthreads();
    bf16x8 af[4], bfr[4];
#pragma unroll
    for (int mi = 0; mi < 4; ++mi)
      af[mi] = *(const bf16x8*)(sA + (wm + mi * 16 + l15) * 32 + quad * 8);
#pragma unroll
    for (int ni = 0; ni < 4; ++ni)
      bfr[ni] = *(const bf16x8*)(sB + (wn + ni * 16 + l15) * 32 + quad * 8);
#pragma unroll
    for (int mi = 0; mi < 4; ++mi)
#pragma unroll
      for (int ni = 0; ni < 4; ++ni)
        acc[mi][ni] = __builtin_amdgcn_mfma_f32_16x16x32_bf16(
            af[mi], bfr[ni], acc[mi][ni], 0, 0, 0);
  }

#pragma unroll
  for (int ni = 0; ni < 4; ++ni) {
    int col = bn * 128 + wn + ni * 16 + l15;
    float bv = bias[col];
#pragma unroll
    for (int mi = 0; mi < 4; ++mi) {
#pragma unroll
      for (int reg = 0; reg < 4; ++reg) {
        int row = bm * 128 + wm + mi * 16 + quad * 4 + reg;
        out[(size_t)row * THREE_EMBED + col] = f2b(acc[mi][ni][reg] + bv);
      }
    }
  }
}

// ---------------------------------------------------------------------------
// Attention: one block per (window, head). Gather + RoPE fused into loads.
// K/V staged per 128-key half (online softmax across halves). LDS ~38KB.
// All 256 threads stage (half a K row + half a V row each).
// ---------------------------------------------------------------------------
__global__ __launch_bounds__(256) void attn(
    const unsigned short* __restrict__ qkv,
    const float* __restrict__ rope_cos, const float* __restrict__ rope_sin,
    const int* __restrict__ kvi,
    unsigned short* __restrict__ ori)
{
  __shared__ __align__(16) unsigned short sK[128 * 64];   // [key][d] swizzled
  __shared__ __align__(16) unsigned short sV[64 * 128];   // [d][key] swizzled
  __shared__ __align__(16) unsigned short sP[4][16 * 40]; // per-wave P chunk

  const int t = threadIdx.x;
  const int lane = t & 63, wid = t >> 6;
  const int l15 = lane & 15, quad = lane >> 4;
  const int wwin = blockIdx.x >> 4;
  const int h = blockIdx.x & 15;

  f32x4 accO[4][4];
  float mrow[4][4], lrow[4][4];
#pragma unroll
  for (int qt = 0; qt < 4; ++qt) {
#pragma unroll
    for (int nt = 0; nt < 4; ++nt) accO[qt][nt] = (f32x4){0.f, 0.f, 0.f, 0.f};
#pragma unroll
    for (int reg = 0; reg < 4; ++reg) { mrow[qt][reg] = -1e30f; lrow[qt][reg] = 0.f; }
  }

  // Preload Q fragments (RoPE + 1/sqrt(64) scale folded in).
  bf16x8 qa[4][2];
#pragma unroll
  for (int qt = 0; qt < 4; ++qt) {
    int qrow = wid * 64 + qt * 16 + l15;
    int i = wwin * 256 + qrow;
    int g = kvi[i];
    const unsigned short* qp = qkv + (size_t)g * THREE_EMBED + h * HDIM;
    bf16x8 qlo = *(const bf16x8*)(qp + quad * 8);
    bf16x8 qhi = *(const bf16x8*)(qp + 32 + quad * 8);
    const float* cp = rope_cos + (size_t)i * HDIM;
    const float* sp = rope_sin + (size_t)i * HDIM;
    float c0[8], c1[8], s0[8], s1[8];
    *(float4*)(c0) = *(const float4*)(cp + quad * 8);
    *(float4*)(c0 + 4) = *(const float4*)(cp + quad * 8 + 4);
    *(float4*)(c1) = *(const float4*)(cp + 32 + quad * 8);
    *(float4*)(c1 + 4) = *(const float4*)(cp + 32 + quad * 8 + 4);
    *(float4*)(s0) = *(const float4*)(sp + quad * 8);
    *(float4*)(s0 + 4) = *(const float4*)(sp + quad * 8 + 4);
    *(float4*)(s1) = *(const float4*)(sp + 32 + quad * 8);
    *(float4*)(s1 + 4) = *(const float4*)(sp + 32 + quad * 8 + 4);
    bf16x8 f0, f1;
#pragma unroll
    for (int j = 0; j < 8; ++j) {
      float ql = b2f((unsigned short)qlo[j]);
      float qh = b2f((unsigned short)qhi[j]);
      float v0 = (ql * c0[j] - qh * s0[j]) * 0.125f;
      float v1 = (qh * c1[j] + ql * s1[j]) * 0.125f;
      f0[j] = (short)f2b(v0);
      f1[j] = (short)f2b(v1);
    }
    qa[qt][0] = f0;
    qa[qt][1] = f1;
  }

  for (int half = 0; half < 2; ++half) {
    __syncthreads();
    {
      int key = t >> 1, hx = t & 1;  // each thread: 32 d-values of one key
      int i = wwin * 256 + half * 128 + key;
      int g = kvi[i];
      const unsigned short* kp = qkv + (size_t)g * THREE_EMBED + EMBED + h * HDIM;
      const float* cp = rope_cos + (size_t)i * HDIM + hx * 32;
      const float* sp = rope_sin + (size_t)i * HDIM + hx * 32;
      const float sgn = hx ? 1.f : -1.f;
#pragma unroll
      for (int c = 0; c < 4; ++c) {
        int dbase = hx * 32 + c * 8;
        bf16x8 ka = *(const bf16x8*)(kp + dbase);
        bf16x8 kb = *(const bf16x8*)(kp + (dbase ^ 32));
        float cc[8], ss[8];
        *(float4*)(cc) = *(const float4*)(cp + c * 8);
        *(float4*)(cc + 4) = *(const float4*)(cp + c * 8 + 4);
        *(float4*)(ss) = *(const float4*)(sp + c * 8);
        *(float4*)(ss + 4) = *(const float4*)(sp + c * 8 + 4);
        union { unsigned short u[8]; uint4 v; } pk;
#pragma unroll
        for (int j = 0; j < 8; ++j) {
          float kd = b2f((unsigned short)ka[j]);
          float kq = b2f((unsigned short)kb[j]);
          pk.u[j] = f2b(kd * cc[j] + sgn * kq * ss[j]);
        }
        *(uint4*)(sK + key * 64 + (((dbase >> 3) ^ (key & 7)) * 8)) = pk.v;
      }
      const unsigned short* vp = qkv + (size_t)g * THREE_EMBED + 2 * EMBED + h * HDIM;
      int kc3 = key >> 3, k7 = key & 7;
#pragma unroll
      for (int c = 0; c < 4; ++c) {
        bf16x8 va = *(const bf16x8*)(vp + hx * 32 + c * 8);
#pragma unroll
        for (int j = 0; j < 8; ++j) {
          int d = hx * 32 + c * 8 + j;
          sV[d * 128 + ((kc3 ^ (d & 7)) * 8) + k7] = (unsigned short)va[j];
        }
      }
    }
    __syncthreads();

#pragma unroll
    for (int qt = 0; qt < 4; ++qt) {
      f32x4 accS[8];
#pragma unroll
      for (int nt = 0; nt < 8; ++nt) accS[nt] = (f32x4){0.f, 0.f, 0.f, 0.f};
#pragma unroll
      for (int ks = 0; ks < 2; ++ks) {
#pragma unroll
        for (int nt = 0; nt < 8; ++nt) {
          int key = nt * 16 + l15;
          bf16x8 bk = *(const bf16x8*)(
              sK + key * 64 + (((ks * 4 + quad) ^ (key & 7)) * 8));
          accS[nt] = __builtin_amdgcn_mfma_f32_16x16x32_bf16(
              qa[qt][ks], bk, accS[nt], 0, 0, 0);
        }
      }
#pragma unroll
      for (int reg = 0; reg < 4; ++reg) {
        float mx = accS[0][reg];
#pragma unroll
        for (int nt = 1; nt < 8; ++nt) mx = fmaxf(mx, accS[nt][reg]);
#pragma unroll
        for (int off = 1; off < 16; off <<= 1)
          mx = fmaxf(mx, __shfl_xor(mx, off, 64));
        float mold = mrow[qt][reg];
        float mnew = fmaxf(mold, mx);
        float alpha = __expf(mold - mnew);
        mrow[qt][reg] = mnew;
        float ls = 0.f;
#pragma unroll
        for (int nt = 0; nt < 8; ++nt) {
          float p = __expf(accS[nt][reg] - mnew);
          accS[nt][reg] = p;
          ls += p;
        }
#pragma unroll
        for (int off = 1; off < 16; off <<= 1) ls += __shfl_xor(ls, off, 64);
        lrow[qt][reg] = lrow[qt][reg] * alpha + ls;
#pragma unroll
        for (int nt = 0; nt < 4; ++nt) accO[qt][nt][reg] *= alpha;
      }
#pragma unroll
      for (int kc = 0; kc < 4; ++kc) {
#pragma unroll
        for (int nt2 = 0; nt2 < 2; ++nt2) {
#pragma unroll
          for (int reg = 0; reg < 4; ++reg) {
            sP[wid][(quad * 4 + reg) * 40 + nt2 * 16 + l15] =
                f2b(accS[kc * 2 + nt2][reg]);
          }
        }
        bf16x8 pa = *(const bf16x8*)(&sP[wid][l15 * 40 + quad * 8]);
#pragma unroll
        for (int nt = 0; nt < 4; ++nt) {
          int d = nt * 16 + l15;
          bf16x8 bv = *(const bf16x8*)(
              sV + d * 128 + (((kc * 4 + quad) ^ (d & 7)) * 8));
          accO[qt][nt] = __builtin_amdgcn_mfma_f32_16x16x32_bf16(
              pa, bv, accO[qt][nt], 0, 0, 0);
        }
      }
    }
  }

#pragma unroll
  for (int qt = 0; qt < 4; ++qt) {
#pragma unroll
    for (int reg = 0; reg < 4; ++reg) {
      int qrow = wid * 64 + qt * 16 + quad * 4 + reg;
      int i = wwin * 256 + qrow;
      int orow = kvi[i];
      float inv = 1.0f / lrow[qt][reg];
      unsigned short* op = ori + (size_t)orow * EMBED + h * HDIM;
#pragma unroll
      for (int nt = 0; nt < 4; ++nt) {
        op[nt * 16 + l15] = f2b(accO[qt][nt][reg] * inv);
      }
    }
  }
}

// ---------------------------------------------------------------------------
// GEMM2: out = ori[:L] @ proj_w^T + proj_b. A bf16 via global_load_lds;
// B fp32 inline-converted; out fp32.
// ---------------------------------------------------------------------------
__global__ __launch_bounds__(256) void gemm_proj(
    const unsigned short* __restrict__ A, const float* __restrict__ w,
    const float* __restrict__ bias, float* __restrict__ out)
{
  __shared__ __align__(16) unsigned short sA[128 * 32];
  __shared__ __align__(16) unsigned short sB[128 * 32];
  const int t = threadIdx.x;
  const int lane = t & 63, wid = t >> 6;
  const int l15 = lane & 15, quad = lane >> 4;
  const int wm = (wid >> 1) * 64, wn = (wid & 1) * 64;
  const int bm = blockIdx.x, bn = blockIdx.y;

  const int r0 = t >> 2, c8 = (t & 3) * 8;
  const unsigned short* gA0 = A + (size_t)(bm * 128 + r0) * EMBED + c8;
  unsigned short* lA0 = sA + wid * 512;
  unsigned short* lA1 = sA + 2048 + wid * 512;
  const int rb = t >> 3, cb = t & 7;

  f32x4 acc[4][4];
#pragma unroll
  for (int i = 0; i < 4; ++i)
#pragma unroll
    for (int j = 0; j < 4; ++j) acc[i][j] = (f32x4){0.f, 0.f, 0.f, 0.f};

  for (int k0 = 0; k0 < EMBED; k0 += 32) {
    __syncthreads();
    gload16(gA0 + k0, lA0);
    gload16(gA0 + 64 * EMBED + k0, lA1);
#pragma unroll
    for (int ri = 0; ri < 4; ++ri) {
      int r = rb + 32 * ri;
      float4 v = *(const float4*)(w + (size_t)(bn * 128 + r) * EMBED + k0 + cb * 4);
      ushort4 b;
      b.x = f2b(v.x); b.y = f2b(v.y); b.z = f2b(v.z); b.w = f2b(v.w);
      *(ushort4*)(sB + r * 32 + cb * 4) = b;
    }
    __syncthreads();
    bf16x8 af[4], bfr[4];
#pragma unroll
    for (int mi = 0; mi < 4; ++mi)
      af[mi] = *(const bf16x8*)(sA + (wm + mi * 16 + l15) * 32 + quad * 8);
#pragma unroll
    for (int ni = 0; ni < 4; ++ni)
      bfr[ni] = *(const bf16x8*)(sB + (wn + ni * 16 + l15) * 32 + quad * 8);
#pragma unroll
    for (int mi = 0; mi < 4; ++mi)
#pragma unroll
      for (int ni = 0; ni < 4; ++ni)
        acc[mi][ni] = __builtin_amdgcn_mfma_f32_16x16x32_bf16(
            af[mi], bfr[ni], acc[mi][ni], 0, 0, 0);
  }

#pragma unroll
  for (int ni = 0; ni < 4; ++ni) {
    int col = bn * 128 + wn + ni * 16 + l15;
    float bv = bias[col];
#pragma unroll
    for (int mi = 0; mi < 4; ++mi) {
#pragma unroll
      for (int reg = 0; reg < 4; ++reg) {
        int row = bm * 128 + wm + mi * 16 + quad * 4 + reg;
        if (row < LTOT) out[(size_t)row * EMBED + col] = acc[mi][ni][reg] + bv;
      }
    }
  }
}

// ---------------------------------------------------------------------------
extern "C" void kernel_launch(void* const* d_in, const int* in_sizes, int n_in,
                              void* d_out, int out_size, void* d_ws, size_t ws_size,
                              hipStream_t stream) {
  const float* x        = (const float*)d_in[0];
  const float* qkv_w    = (const float*)d_in[1];
  const float* qkv_b    = (const float*)d_in[2];
  const float* proj_w   = (const float*)d_in[3];
  const float* proj_b   = (const float*)d_in[4];
  const float* padding  = (const float*)d_in[5];
  const float* rope_cos = (const float*)d_in[6];
  const float* rope_sin = (const float*)d_in[7];
  const int*   kvi      = (const int*)d_in[8];

  // ws layout (134.2 MB total, proven safe in R1):
  //   [0, 100.66M):  qkv_bf  (16384x3072 bf16)
  //   [100.66M, +33.55M): R — xb (cast+gemm_qkv) then ori (attn+gemm_proj);
  //                        lifetimes disjoint.
  // wqb (6.3 MB) lives at the head of d_out — dead before gemm_proj writes it.
  unsigned short* qkv_bf = (unsigned short*)d_ws;
  unsigned short* R      = (unsigned short*)((char*)d_ws +
                              (size_t)MTOT * THREE_EMBED * 2);
  unsigned short* xb  = R;
  unsigned short* ori = R;
  unsigned short* wqb = (unsigned short*)d_out;
  float* out = (float*)d_out;

  cast_inputs<<<4096, 256, 0, stream>>>(x, padding, qkv_w, xb, wqb);
  gemm_qkv<<<dim3(128, 24), 256, 0, stream>>>(xb, wqb, qkv_b, qkv_bf);
  attn<<<dim3(64 * 16), 256, 0, stream>>>(qkv_bf, rope_cos, rope_sin, kvi, ori);
  gemm_proj<<<dim3(128, 8), 256, 0, stream>>>(ori, proj_w, proj_b, out);
}